// Round 5
// baseline (340.325 us; speedup 1.0000x reference)
//
#include <hip/hip_runtime.h>
#include <hip/hip_bf16.h>

// Squared Euclidean distance: out[i][j] = ||a_i||^2 + ||b_j||^2 - 2 a_i.b_j
// a: [8192,128] fp32, b: [8192,128] fp32, out: [8192,8192] fp32.
//
// v5b (= v5 + compile fix: nontemporal store needs a native clang vector type,
// not HIP_vector_type float4):
//   Rounds 0/2/3 proved the kernel is NOT LDS- or VALU-bound (swizzle +
//   packed-cvt moved nothing). Inferred dist time ~100us = 2.6 TB/s effective
//   store BW: the epilogue's 64B-segment column-slab store pattern is DRAM-page
//   hostile and churns L2. This version:
//   1. Stages the 128x128 f32 output tile in LDS (reusing the operand buffer)
//      and stores with 512B-contiguous global_store_dwordx4 (2 rows/instr).
//   2. Nontemporal stores (write-once output; keeps A/B panels in L2).
//   3. Fuses row-norm computation into tile staging (16-lane shfl reduce into
//      a small LDS array) -- single kernel, no workspace.
// Write-bound floor: 268 MB out @6.3TB/s => ~43us.

typedef __attribute__((ext_vector_type(8))) short bf16x8;   // 8 bf16 = 4 VGPRs
typedef __attribute__((ext_vector_type(4))) float f32x4;    // MFMA acc / stores

#define BM 128
#define BN 128

__device__ __forceinline__ bf16x8 cvt8(float4 v0, float4 v1) {
    union { bf16x8 v; __hip_bfloat162 h[4]; } u;
    u.h[0] = __float22bfloat162_rn(make_float2(v0.x, v0.y));
    u.h[1] = __float22bfloat162_rn(make_float2(v0.z, v0.w));
    u.h[2] = __float22bfloat162_rn(make_float2(v1.x, v1.y));
    u.h[3] = __float22bfloat162_rn(make_float2(v1.z, v1.w));
    return u.v;
}

__global__ __launch_bounds__(256, 2)
void dist_kernel(const float* __restrict__ A, const float* __restrict__ B,
                 float* __restrict__ out, int N2) {
    // [0,32K)=A bf16 tile, [32K,64K)=B bf16 tile; output tile reuses [0,64K)
    // after MFMA. [64K,64K+512)=nA, [+512,+1K)=nB.
    __shared__ char lds[66560];
    float* nA = (float*)(lds + 65536);
    float* nB = (float*)(lds + 66048);

    const int tid  = threadIdx.x;
    const int wave = tid >> 6;             // 0..3
    const int lane = tid & 63;
    const int q    = lane >> 4;            // quad 0..3
    const int l15  = lane & 15;

    const int ti = blockIdx.y * BM;        // rows of mat1
    const int tj = blockIdx.x * BN;        // rows of mat2 (= cols of out)

    // ---- phase 1: stage tiles (fp32->bf16, swizzled) + fused row norms ----
    // LDS element (row,k) at byte row*256 + ((2k) ^ ((row&7)<<4)).
    // Norms: each row's 16 staging threads (consecutive, 16-aligned lanes)
    // shfl-reduce their 8-elem partial ssq.
#pragma unroll
    for (int g = 0; g < 8; ++g) {
        int idx = tid + g * 256;           // 0..2047
        int row = idx >> 4;                // 0..127
        int ke  = (idx & 15) * 8;          // element col of 8-elem chunk
        int sw  = (ke * 2) ^ ((row & 7) << 4);
        const float4* pa = (const float4*)(A + (size_t)(ti + row) * 128 + ke);
        float4 v0 = pa[0], v1 = pa[1];
        *(bf16x8*)(lds + row * 256 + sw) = cvt8(v0, v1);
        float s = v0.x*v0.x + v0.y*v0.y + v0.z*v0.z + v0.w*v0.w
                + v1.x*v1.x + v1.y*v1.y + v1.z*v1.z + v1.w*v1.w;
        s += __shfl_xor(s, 1); s += __shfl_xor(s, 2);
        s += __shfl_xor(s, 4); s += __shfl_xor(s, 8);
        if ((idx & 15) == 0) nA[row] = s;
    }
#pragma unroll
    for (int g = 0; g < 8; ++g) {
        int idx = tid + g * 256;
        int row = idx >> 4;
        int ke  = (idx & 15) * 8;
        int sw  = (ke * 2) ^ ((row & 7) << 4);
        const float4* pb = (const float4*)(B + (size_t)(tj + row) * 128 + ke);
        float4 v0 = pb[0], v1 = pb[1];
        *(bf16x8*)(lds + 32768 + row * 256 + sw) = cvt8(v0, v1);
        float s = v0.x*v0.x + v0.y*v0.y + v0.z*v0.z + v0.w*v0.w
                + v1.x*v1.x + v1.y*v1.y + v1.z*v1.z + v1.w*v1.w;
        s += __shfl_xor(s, 1); s += __shfl_xor(s, 2);
        s += __shfl_xor(s, 4); s += __shfl_xor(s, 8);
        if ((idx & 15) == 0) nB[row] = s;
    }
    __syncthreads();

    const int wm = (wave >> 1) * 64;       // wave's 64x64 sub-tile
    const int wn = (wave & 1) * 64;

    f32x4 acc[4][4] = {};                  // zero-init

    // ---- phase 2: MFMA over K=128 ----
    // A frag: lane holds A[m=l15][k=q*8+j]; B frag: B[k=q*8+j][n=l15]
    const char* Abase = lds;
    const char* Bbase = lds + 32768;
#pragma unroll
    for (int kk = 0; kk < 128; kk += 32) {
        const int cb = kk * 2 + q * 16;    // byte col of this lane's 8 bf16
        bf16x8 af[4], bfr[4];
#pragma unroll
        for (int mi = 0; mi < 4; ++mi) {
            int row = wm + mi * 16 + l15;
            af[mi] = *(const bf16x8*)(Abase + row * 256 + (cb ^ ((row & 7) << 4)));
        }
#pragma unroll
        for (int ni = 0; ni < 4; ++ni) {
            int row = wn + ni * 16 + l15;
            bfr[ni] = *(const bf16x8*)(Bbase + row * 256 + (cb ^ ((row & 7) << 4)));
        }
#pragma unroll
        for (int mi = 0; mi < 4; ++mi)
#pragma unroll
            for (int ni = 0; ni < 4; ++ni)
                acc[mi][ni] = __builtin_amdgcn_mfma_f32_16x16x32_bf16(
                    af[mi], bfr[ni], acc[mi][ni], 0, 0, 0);
    }

    // ---- phase 3: pull norms into regs (separate LDS region, safe) ----
    float an[4][4], bn[4];
#pragma unroll
    for (int mi = 0; mi < 4; ++mi) {
        float4 t = *(const float4*)&nA[wm + mi * 16 + q * 4];
        an[mi][0] = t.x; an[mi][1] = t.y; an[mi][2] = t.z; an[mi][3] = t.w;
    }
#pragma unroll
    for (int ni = 0; ni < 4; ++ni) bn[ni] = nB[wn + ni * 16 + l15];

    __syncthreads();   // all waves done reading operand tiles

    // ---- phase 4: write output tile to LDS ----
    // tile [128 rows][128 dwords], row stride 512B,
    // element (row,c) at byte row*512 + ((4c) ^ (((row>>2)&1)<<6)).
    // C/D layout: col = l15, row = q*4 + reg (verified m89/m91).
#pragma unroll
    for (int mi = 0; mi < 4; ++mi) {
#pragma unroll
        for (int ni = 0; ni < 4; ++ni) {
            int c = wn + ni * 16 + l15;
            f32x4 v = acc[mi][ni];
#pragma unroll
            for (int j = 0; j < 4; ++j) {
                int row = wm + mi * 16 + q * 4 + j;
                *(float*)(lds + row * 512 + ((c * 4) ^ (((row >> 2) & 1) << 6)))
                    = an[mi][j] + bn[ni] - 2.0f * v[j];
            }
        }
    }
    __syncthreads();   // full block tile staged (rows mix both wn halves)

    // ---- phase 5: stream out, 512B contiguous per row, nontemporal ----
    // wave handles rows [wave*32, wave*32+32); 2 rows per pass.
    const int l31 = lane & 31;
    const int h   = lane >> 5;
#pragma unroll
    for (int p = 0; p < 16; ++p) {
        int row = wave * 32 + p * 2 + h;
        int cb  = (l31 * 16) ^ (((row >> 2) & 1) << 6);
        f32x4 v = *(const f32x4*)(lds + row * 512 + cb);
        __builtin_nontemporal_store(
            v, (f32x4*)(out + (size_t)(ti + row) * N2 + tj + l31 * 4));
    }
}

extern "C" void kernel_launch(void* const* d_in, const int* in_sizes, int n_in,
                              void* d_out, int out_size, void* d_ws, size_t ws_size,
                              hipStream_t stream) {
    const float* m1 = (const float*)d_in[0];
    const float* m2 = (const float*)d_in[1];
    float* out = (float*)d_out;
    const int rows1 = in_sizes[0] / 128;   // 8192
    const int rows2 = in_sizes[1] / 128;   // 8192

    dim3 grid(rows2 / BN, rows1 / BM);
    dist_kernel<<<grid, 256, 0, stream>>>(m1, m2, out, rows2);
}